// Round 10
// baseline (519.626 us; speedup 1.0000x reference)
//
#include <hip/hip_runtime.h>

#define N_NODES 50000
#define N_EDGES 800000
#define BN_EPS 1e-5f
#define K_BUCK 196        // dst >> 8 buckets (256 nodes each)
#define PART_B 256        // partition blocks
#define CHUNK 3125        // N_EDGES / PART_B

typedef __attribute__((ext_vector_type(8))) short bshort8;
typedef __attribute__((ext_vector_type(4))) float f32x4;

__device__ inline float bf2f(unsigned int u16) {
    return __uint_as_float(u16 << 16);
}
__device__ inline unsigned short f2bf(float f) {
    unsigned int u = __float_as_uint(f);
    u = (u + 0x7FFFu + ((u >> 16) & 1u)) >> 16;
    return (unsigned short)u;
}

// ---------------- scan helpers ----------------

__device__ inline int block_exscan256(int v, int tid, int* total) {
    int lane = tid & 63;
    int wave = tid >> 6;
    int incl = v;
#pragma unroll
    for (int off = 1; off < 64; off <<= 1) {
        int t = __shfl_up(incl, off, 64);
        if (lane >= off) incl += t;
    }
    __shared__ int wsum[4];
    if (lane == 63) wsum[wave] = incl;
    __syncthreads();
    int w0 = wsum[0], w1 = wsum[1], w2 = wsum[2], w3 = wsum[3];
    __syncthreads();
    int wofs = (wave > 0 ? w0 : 0) + (wave > 1 ? w1 : 0) + (wave > 2 ? w2 : 0);
    *total = w0 + w1 + w2 + w3;
    return wofs + incl - v;
}

__global__ __launch_bounds__(256) void scan_reduce_kernel(const int* __restrict__ in,
                                                          int* __restrict__ bsum, int n) {
    int tid = threadIdx.x;
    int i = blockIdx.x * 256 + tid;
    int v = (i < n) ? in[i] : 0;
    int lane = tid & 63;
    int wave = tid >> 6;
#pragma unroll
    for (int off = 32; off > 0; off >>= 1) v += __shfl_down(v, off, 64);
    __shared__ int wsum[4];
    if (lane == 0) wsum[wave] = v;
    __syncthreads();
    if (tid == 0) bsum[blockIdx.x] = wsum[0] + wsum[1] + wsum[2] + wsum[3];
}

__global__ __launch_bounds__(256) void scan_bsum_kernel(int* __restrict__ bsum, int B) {
    int tid = threadIdx.x;
    int v = (tid < B) ? bsum[tid] : 0;
    int total;
    int excl = block_exscan256(v, tid, &total);
    if (tid < B) bsum[tid] = excl;
}

__global__ __launch_bounds__(256) void scan_apply_kernel(const int* __restrict__ in,
                                                         const int* __restrict__ bsum,
                                                         int* __restrict__ out, int n) {
    int tid = threadIdx.x;
    int i = blockIdx.x * 256 + tid;
    int v = (i < n) ? in[i] : 0;
    int total;
    int excl = block_exscan256(v, tid, &total);
    if (i < n) out[i] = bsum[blockIdx.x] + excl;
}

// ---- bucketed CSR build ----

__global__ __launch_bounds__(256) void bucket_count_kernel(const int* __restrict__ dst,
                                                           int* __restrict__ deg,
                                                           int* __restrict__ cnt) {
    __shared__ int lcnt[K_BUCK];
    int tid = threadIdx.x;
    for (int i = tid; i < K_BUCK; i += 256) lcnt[i] = 0;
    __syncthreads();
    int start = blockIdx.x * CHUNK;
    for (int it = tid; it < CHUNK; it += 256) {
        int d = dst[start + it];
        atomicAdd(&lcnt[d >> 8], 1);
        atomicAdd(&deg[d], 1);
    }
    __syncthreads();
    for (int i = tid; i < K_BUCK; i += 256) cnt[i * PART_B + blockIdx.x] = lcnt[i];
}

__global__ __launch_bounds__(256) void partition_kernel(const int* __restrict__ src,
                                                        const int* __restrict__ dst,
                                                        const int* __restrict__ base,
                                                        uint2* __restrict__ P) {
    __shared__ int lofs[K_BUCK];
    int tid = threadIdx.x;
    for (int i = tid; i < K_BUCK; i += 256) lofs[i] = base[i * PART_B + blockIdx.x];
    __syncthreads();
    int start = blockIdx.x * CHUNK;
    for (int it = tid; it < CHUNK; it += 256) {
        int e = start + it;
        int d = dst[e], s = src[e];
        int p = atomicAdd(&lofs[d >> 8], 1);
        P[p] = make_uint2((unsigned)d, (unsigned)s);
    }
}

__global__ __launch_bounds__(256) void fine_scatter_kernel(const uint2* __restrict__ P,
                                                           const int* __restrict__ base,
                                                           const int* __restrict__ deg,
                                                           int* __restrict__ rowptr,
                                                           int* __restrict__ col) {
    __shared__ int wloc[256];
    int b = blockIdx.x;
    int tid = threadIdx.x;
    int nbase = b << 8;
    int nn = min(256, N_NODES - nbase);
    int d = (tid < nn) ? deg[nbase + tid] : 0;
    int total;
    int excl = block_exscan256(d, tid, &total);
    int start = base[b * PART_B];
    int rp = start + excl;
    if (tid < nn) {
        rowptr[nbase + tid] = rp;
        wloc[tid] = rp;
    }
    if (b == K_BUCK - 1 && tid == 0) rowptr[N_NODES] = N_EDGES;
    __syncthreads();
    int end = (b + 1 < K_BUCK) ? base[(b + 1) * PART_B] : N_EDGES;
    for (int e = start + tid; e < end; e += 256) {
        uint2 pr = P[e];
        int rank = atomicAdd(&wloc[pr.x - nbase], 1);
        col[rank] = (int)pr.y;
    }
}

// ---------------- conversions ----------------

struct WT8 {
    const float* src[8];
    unsigned short* dst[8];
    int K[8];
    int N[8];
};

__global__ __launch_bounds__(256) void wtconv_kernel(WT8 p) {
    int wi = blockIdx.y;
    int K = p.K[wi], N = p.N[wi];
    int idx = blockIdx.x * 256 + threadIdx.x;
    if (idx >= K * N) return;
    int logn = 31 - __clz(N);
    int n = idx & (N - 1);
    int k = idx >> logn;
    p.dst[wi][(size_t)n * K + k] = f2bf(p.src[wi][idx]);
}

// ---------------- aggregation (bf16) ----------------

__device__ inline void acc8(uint4 v, float* a) {
    a[0] += bf2f(v.x & 0xFFFFu); a[1] += __uint_as_float(v.x & 0xFFFF0000u);
    a[2] += bf2f(v.y & 0xFFFFu); a[3] += __uint_as_float(v.y & 0xFFFF0000u);
    a[4] += bf2f(v.z & 0xFFFFu); a[5] += __uint_as_float(v.z & 0xFFFF0000u);
    a[6] += bf2f(v.w & 0xFFFFu); a[7] += __uint_as_float(v.w & 0xFFFF0000u);
}

template <int LPN, bool RELU>
__global__ __launch_bounds__(256) void aggregate_bf16_kernel(
    const unsigned short* __restrict__ h, const int* __restrict__ rowptr,
    const int* __restrict__ col, const float* __restrict__ bias,
    unsigned short* __restrict__ z, int n) {
    const int gpb = 256 / LPN;
    int gid = threadIdx.x / LPN;
    int l = threadIdx.x % LPN;
    int node = blockIdx.x * gpb + gid;
    if (node >= n) return;
    const uint4* hv = (const uint4*)h;
    float a[8] = {};
    acc8(hv[(size_t)node * LPN + l], a);  // self
    int s = rowptr[node], epos = rowptr[node + 1];
    for (int e = s; e < epos; ++e) {
        int j = col[e];
        acc8(hv[(size_t)j * LPN + l], a);
    }
    if (RELU) {
        float4 b0 = *(const float4*)(bias + l * 8);
        float4 b1 = *(const float4*)(bias + l * 8 + 4);
        a[0] = fmaxf(a[0] + b0.x, 0.f); a[1] = fmaxf(a[1] + b0.y, 0.f);
        a[2] = fmaxf(a[2] + b0.z, 0.f); a[3] = fmaxf(a[3] + b0.w, 0.f);
        a[4] = fmaxf(a[4] + b1.x, 0.f); a[5] = fmaxf(a[5] + b1.y, 0.f);
        a[6] = fmaxf(a[6] + b1.z, 0.f); a[7] = fmaxf(a[7] + b1.w, 0.f);
    }
    uint4 o;
    o.x = (unsigned int)f2bf(a[0]) | ((unsigned int)f2bf(a[1]) << 16);
    o.y = (unsigned int)f2bf(a[2]) | ((unsigned int)f2bf(a[3]) << 16);
    o.z = (unsigned int)f2bf(a[4]) | ((unsigned int)f2bf(a[5]) << 16);
    o.w = (unsigned int)f2bf(a[6]) | ((unsigned int)f2bf(a[7]) << 16);
    ((uint4*)z)[(size_t)node * LPN + l] = o;
}

// ---------------- epilogue scale/shift helper ----------------

__device__ inline void epi_coeff(int mode, int c, const float* bias, const float* g,
                                 const float* be, const float* mu, const float* var,
                                 float* s, float* sh) {
    *s = 1.f; *sh = 0.f;
    if (mode == 0) {
        *sh = bias[c];
    } else if (mode == 1) {
        float t = g[c] * rsqrtf(var[c] + BN_EPS);
        *s = t;
        *sh = be[c] - mu[c] * t + bias[c] * t;
    }
}

// ---------------- bf16 MFMA GEMM v2 + XCD swizzle (+ optional fused classifier) ----

template <int NT, bool F32A, bool CLS>
__global__ __launch_bounds__(256) void mfma_gemm2_kernel(
    const void* __restrict__ Ain, const unsigned short* __restrict__ Wt,
    const float* __restrict__ bias, unsigned short* __restrict__ C,
    int M, int K, int Nn, int mode, int gxblocks, int gy,
    const float* __restrict__ g, const float* __restrict__ be,
    const float* __restrict__ mu, const float* __restrict__ var,
    const float* __restrict__ wcls, const float* __restrict__ bcls,
    float* __restrict__ outp) {
    constexpr int BM = 128, BK = 64;
    constexpr int BN = NT * 16;
    constexpr int LDA = BK + 8;
    constexpr int LDB = BK + 8;
    constexpr int LDE = BN + 8;
    constexpr int NB_LD = (BN * BK / 8) / 256;
    __shared__ __align__(16) unsigned short smem[BM * LDA + BN * LDB];
    unsigned short* As = smem;
    unsigned short* Bs = smem + BM * LDA;
    unsigned short* Ep = smem;

    int id = blockIdx.x;
    int lo = id & 7;
    int t = id >> 3;
    int y = t % gy;
    int x = ((t / gy) << 3) | lo;
    if (x >= gxblocks) return;

    const int tid = threadIdx.x;
    const int wv = tid >> 6;
    const int ln = tid & 63;
    const int l15 = ln & 15;
    const int quad = ln >> 4;
    const int row0 = x * BM;
    const int col0 = y * BN;

    const unsigned short* A16 = (const unsigned short*)Ain;
    const float* A32 = (const float*)Ain;

    uint4 Ar[4], Br[NB_LD];

    auto loadA = [&](int k0) {
#pragma unroll
        for (int u = 0; u < 4; ++u) {
            int idx2 = tid + 256 * u;
            int r = idx2 >> 3, cg = (idx2 & 7) * 8;
            int gr = row0 + r;
            if (gr >= M) gr = M - 1;
            if (F32A) {
                float4 f0 = *(const float4*)(A32 + (size_t)gr * K + k0 + cg);
                float4 f1 = *(const float4*)(A32 + (size_t)gr * K + k0 + cg + 4);
                uint4 o;
                o.x = (unsigned)f2bf(f0.x) | ((unsigned)f2bf(f0.y) << 16);
                o.y = (unsigned)f2bf(f0.z) | ((unsigned)f2bf(f0.w) << 16);
                o.z = (unsigned)f2bf(f1.x) | ((unsigned)f2bf(f1.y) << 16);
                o.w = (unsigned)f2bf(f1.z) | ((unsigned)f2bf(f1.w) << 16);
                Ar[u] = o;
            } else {
                Ar[u] = *(const uint4*)(A16 + (size_t)gr * K + k0 + cg);
            }
        }
    };
    auto loadB = [&](int k0) {
#pragma unroll
        for (int u = 0; u < NB_LD; ++u) {
            int idx2 = tid + 256 * u;
            int r = idx2 >> 3, cg = (idx2 & 7) * 8;
            Br[u] = *(const uint4*)(Wt + (size_t)(col0 + r) * K + k0 + cg);
        }
    };
    auto stage = [&]() {
#pragma unroll
        for (int u = 0; u < 4; ++u) {
            int idx2 = tid + 256 * u;
            int r = idx2 >> 3, cg = (idx2 & 7) * 8;
            *(uint4*)(&As[r * LDA + cg]) = Ar[u];
        }
#pragma unroll
        for (int u = 0; u < NB_LD; ++u) {
            int idx2 = tid + 256 * u;
            int r = idx2 >> 3, cg = (idx2 & 7) * 8;
            *(uint4*)(&Bs[r * LDB + cg]) = Br[u];
        }
    };

    f32x4 acc[2][NT] = {};
    const int KT = K >> 6;
    loadA(0);
    loadB(0);
    for (int kt = 0; kt < KT; ++kt) {
        if (kt > 0) __syncthreads();
        stage();
        __syncthreads();
        if (kt + 1 < KT) {
            loadA((kt + 1) * 64);
            loadB((kt + 1) * 64);
        }
#pragma unroll
        for (int kh = 0; kh < 2; ++kh) {
            bshort8 af[2];
#pragma unroll
            for (int mt = 0; mt < 2; ++mt)
                af[mt] = *(const bshort8*)(&As[(wv * 32 + mt * 16 + l15) * LDA + kh * 32 + quad * 8]);
#pragma unroll
            for (int nt = 0; nt < NT; ++nt) {
                bshort8 bf = *(const bshort8*)(&Bs[(nt * 16 + l15) * LDB + kh * 32 + quad * 8]);
                acc[0][nt] = __builtin_amdgcn_mfma_f32_16x16x32_bf16(af[0], bf, acc[0][nt], 0, 0, 0);
                acc[1][nt] = __builtin_amdgcn_mfma_f32_16x16x32_bf16(af[1], bf, acc[1][nt], 0, 0, 0);
            }
        }
    }

    __syncthreads();
#pragma unroll
    for (int nt = 0; nt < NT; ++nt) {
        int c = col0 + nt * 16 + l15;
        float s, sh;
        epi_coeff(mode, c, bias, g, be, mu, var, &s, &sh);
#pragma unroll
        for (int mt = 0; mt < 2; ++mt) {
            int rl = wv * 32 + mt * 16 + quad * 4;
#pragma unroll
            for (int r = 0; r < 4; ++r) {
                float v = acc[mt][nt][r] * s + sh;
                if (mode != 2) v = fmaxf(v, 0.f);
                Ep[(rl + r) * LDE + nt * 16 + l15] = f2bf(v);
            }
        }
    }
    __syncthreads();
    if (CLS) {
        int r = tid >> 1, j = tid & 1;
        int grow = row0 + r;
        if (grow < M) {
            float s = 0.f;
#pragma unroll 8
            for (int k = 0; k < 64; ++k)
                s += bf2f(Ep[r * LDE + k]) * wcls[k * 2 + j];
            outp[(size_t)grow * 2 + j] = s + bcls[j];
        }
    } else {
        constexpr int CGR = BN / 8;
        constexpr int NU = BM * CGR / 256;
#pragma unroll
        for (int u = 0; u < NU; ++u) {
            int idx2 = tid + 256 * u;
            int r = idx2 / CGR, cg = (idx2 % CGR) * 8;
            int grow = row0 + r;
            if (grow < M)
                *(uint4*)(C + (size_t)grow * Nn + col0 + cg) = *(const uint4*)(&Ep[r * LDE + cg]);
        }
    }
}

// ---------------- fused 2-stage MLP GEMM (register-pipelined B path) ----------------
// C = epi2( epi1(A @ Wt1^T) @ Wt2^T ). BM=64 (full output width -> zero A-refetch).
// B fragments are prefetched one step ahead into explicit register arrays so the
// global->MFMA dependency chain overlaps (R9 post-mortem: VGPR=72 serialized it).

template <int KIN, int DH1, int DH2>
__global__ __launch_bounds__(256) void fused_mlp_kernel(
    const unsigned short* __restrict__ A,
    const unsigned short* __restrict__ Wt1, const unsigned short* __restrict__ Wt2,
    int mode1, const float* __restrict__ b1, const float* __restrict__ g1,
    const float* __restrict__ be1, const float* __restrict__ mu1, const float* __restrict__ var1,
    int mode2, const float* __restrict__ b2, const float* __restrict__ g2,
    const float* __restrict__ be2, const float* __restrict__ mu2, const float* __restrict__ var2,
    unsigned short* __restrict__ C, int M) {
    constexpr int BM = 64, BK = 64;
    constexpr int LDA = BK + 8;
    constexpr int LT1 = DH1 + 8;
    constexpr int LDE = DH2 + 8;
    constexpr int NT1 = DH1 / 32;
    constexpr int NT2 = DH2 / 32;
    constexpr int KT = KIN / 64;
    constexpr int KS2 = DH1 / 32;
    __shared__ __align__(16) unsigned short As[BM * LDA];
    __shared__ __align__(16) unsigned short T1[BM * LT1];   // reused as Ep

    const int tid = threadIdx.x;
    const int wv = tid >> 6;
    const int ln = tid & 63;
    const int l15 = ln & 15;
    const int quad = ln >> 4;
    const int rw = (wv >> 1) * 32;
    const int ch1 = (wv & 1) * (DH1 / 2);
    const int ch2 = (wv & 1) * (DH2 / 2);
    const int row0 = blockIdx.x * BM;

    uint4 Ar[2];
    auto loadA = [&](int k0) {
#pragma unroll
        for (int u = 0; u < 2; ++u) {
            int idx2 = tid + 256 * u;
            int r = idx2 >> 3, cg = (idx2 & 7) * 8;
            int gr = row0 + r;
            if (gr >= M) gr = M - 1;
            Ar[u] = *(const uint4*)(A + (size_t)gr * KIN + k0 + cg);
        }
    };
    auto stageA = [&]() {
#pragma unroll
        for (int u = 0; u < 2; ++u) {
            int idx2 = tid + 256 * u;
            int r = idx2 >> 3, cg = (idx2 & 7) * 8;
            *(uint4*)(&As[r * LDA + cg]) = Ar[u];
        }
    };
    auto loadB1 = [&](int kofs, bshort8* d) {
#pragma unroll
        for (int nt = 0; nt < NT1; ++nt)
            d[nt] = *(const bshort8*)(Wt1 + (size_t)(ch1 + nt * 16 + l15) * KIN + kofs + quad * 8);
    };
    auto loadB2 = [&](int kofs, bshort8* d) {
#pragma unroll
        for (int nt = 0; nt < NT2; ++nt)
            d[nt] = *(const bshort8*)(Wt2 + (size_t)(ch2 + nt * 16 + l15) * DH1 + kofs + quad * 8);
    };

    // ---- stage 1 ----
    f32x4 acc1[2][NT1] = {};
    bshort8 bf[NT1], bnx[NT1];
    loadA(0);
    loadB1(0, bf);
    for (int kt = 0; kt < KT; ++kt) {
        if (kt > 0) __syncthreads();
        stageA();
        __syncthreads();
        if (kt + 1 < KT) loadA((kt + 1) * 64);
#pragma unroll
        for (int kh = 0; kh < 2; ++kh) {
            int knext = kt * 64 + kh * 32 + 32;  // next kh or next kt's kh0
            bool hasnext = knext < KIN;
            if (hasnext) loadB1(knext, bnx);
            bshort8 af[2];
#pragma unroll
            for (int mt = 0; mt < 2; ++mt)
                af[mt] = *(const bshort8*)(&As[(rw + mt * 16 + l15) * LDA + kh * 32 + quad * 8]);
#pragma unroll
            for (int nt = 0; nt < NT1; ++nt) {
                acc1[0][nt] = __builtin_amdgcn_mfma_f32_16x16x32_bf16(af[0], bf[nt], acc1[0][nt], 0, 0, 0);
                acc1[1][nt] = __builtin_amdgcn_mfma_f32_16x16x32_bf16(af[1], bf[nt], acc1[1][nt], 0, 0, 0);
            }
            if (hasnext) {
#pragma unroll
                for (int nt = 0; nt < NT1; ++nt) bf[nt] = bnx[nt];
            }
        }
    }
    // epi1 -> T1 (LDS)
#pragma unroll
    for (int nt = 0; nt < NT1; ++nt) {
        int c = ch1 + nt * 16 + l15;
        float s, sh;
        epi_coeff(mode1, c, b1, g1, be1, mu1, var1, &s, &sh);
#pragma unroll
        for (int mt = 0; mt < 2; ++mt) {
            int rl = rw + mt * 16 + quad * 4;
#pragma unroll
            for (int r = 0; r < 4; ++r) {
                float v = acc1[mt][nt][r] * s + sh;
                if (mode1 != 2) v = fmaxf(v, 0.f);
                T1[(rl + r) * LT1 + c] = f2bf(v);
            }
        }
    }
    __syncthreads();

    // ---- stage 2: A-fragments from T1 (LDS), B register-pipelined ----
    f32x4 acc2[2][NT2] = {};
    bshort8 bf2[NT2], bnx2[NT2];
    loadB2(0, bf2);
#pragma unroll
    for (int ks = 0; ks < KS2; ++ks) {
        if (ks + 1 < KS2) loadB2((ks + 1) * 32, bnx2);
        bshort8 af[2];
#pragma unroll
        for (int mt = 0; mt < 2; ++mt)
            af[mt] = *(const bshort8*)(&T1[(rw + mt * 16 + l15) * LT1 + ks * 32 + quad * 8]);
#pragma unroll
        for (int nt = 0; nt < NT2; ++nt) {
            acc2[0][nt] = __builtin_amdgcn_mfma_f32_16x16x32_bf16(af[0], bf2[nt], acc2[0][nt], 0, 0, 0);
            acc2[1][nt] = __builtin_amdgcn_mfma_f32_16x16x32_bf16(af[1], bf2[nt], acc2[1][nt], 0, 0, 0);
        }
        if (ks + 1 < KS2) {
#pragma unroll
            for (int nt = 0; nt < NT2; ++nt) bf2[nt] = bnx2[nt];
        }
    }
    __syncthreads();  // done reading T1; safe to overwrite as Ep

    unsigned short* Ep = T1;
#pragma unroll
    for (int nt = 0; nt < NT2; ++nt) {
        int c = ch2 + nt * 16 + l15;
        float s, sh;
        epi_coeff(mode2, c, b2, g2, be2, mu2, var2, &s, &sh);
#pragma unroll
        for (int mt = 0; mt < 2; ++mt) {
            int rl = rw + mt * 16 + quad * 4;
#pragma unroll
            for (int r = 0; r < 4; ++r) {
                float v = acc2[mt][nt][r] * s + sh;
                if (mode2 != 2) v = fmaxf(v, 0.f);
                Ep[(rl + r) * LDE + c] = f2bf(v);
            }
        }
    }
    __syncthreads();
    constexpr int CGR = DH2 / 8;
    constexpr int NU = BM * CGR / 256;
#pragma unroll
    for (int u = 0; u < NU; ++u) {
        int idx2 = tid + 256 * u;
        int r = idx2 / CGR, cg = (idx2 % CGR) * 8;
        int grow = row0 + r;
        if (grow < M)
            *(uint4*)(C + (size_t)grow * DH2 + cg) = *(const uint4*)(&Ep[r * LDE + cg]);
    }
}

// ---------------- launch ----------------

extern "C" void kernel_launch(void* const* d_in, const int* in_sizes, int n_in,
                              void* d_out, int out_size, void* d_ws, size_t ws_size,
                              hipStream_t stream) {
    const float* x = (const float*)d_in[0];
    const int* ei = (const int*)d_in[1];
    const int* src = ei;
    const int* dst = ei + N_EDGES;
    const float* w[4][2];
    const float* b[4][2];
    const float* bng[4];
    const float* bnb[4];
    const float* bnm[4];
    const float* bnv[4];
    int idx = 2;
    for (int i = 0; i < 4; ++i) {
        w[i][0] = (const float*)d_in[idx++];
        b[i][0] = (const float*)d_in[idx++];
        w[i][1] = (const float*)d_in[idx++];
        b[i][1] = (const float*)d_in[idx++];
        bng[i] = (const float*)d_in[idx++];
        bnb[i] = (const float*)d_in[idx++];
        bnm[i] = (const float*)d_in[idx++];
        bnv[i] = (const float*)d_in[idx++];
    }
    const float* wc = (const float*)d_in[idx++];
    const float* bc = (const float*)d_in[idx++];
    float* out = (float*)d_out;

    char* ws = (char*)d_ws;
    size_t off = 0;
    auto alloc = [&](size_t bytes) {
        char* p = ws + off;
        off = (off + bytes + 255) & ~(size_t)255;
        return p;
    };
    int* deg = (int*)alloc((size_t)N_NODES * 4);
    int* rowptr = (int*)alloc((size_t)(N_NODES + 1) * 4);
    int* cnt = (int*)alloc((size_t)K_BUCK * PART_B * 4);
    int* bsum2 = (int*)alloc((size_t)K_BUCK * 4);
    int* col = (int*)alloc((size_t)N_EDGES * 4);
    uint2* P = (uint2*)alloc((size_t)N_EDGES * 8);
    unsigned short* bufA = (unsigned short*)alloc((size_t)N_NODES * 256 * 2);
    unsigned short* bufB = (unsigned short*)alloc((size_t)N_NODES * 256 * 2);
    unsigned short* bufC = (unsigned short*)alloc((size_t)N_NODES * 256 * 2);
    const int dims_in[4] = {256, 128, 256, 128};
    const int dims_h[4] = {128, 256, 128, 64};
    unsigned short* wt[4][2];
    for (int L = 0; L < 4; ++L) {
        wt[L][0] = (unsigned short*)alloc((size_t)dims_in[L] * dims_h[L] * 2);
        wt[L][1] = (unsigned short*)alloc((size_t)dims_h[L] * dims_h[L] * 2);
    }
    (void)ws_size;

    // weight transpose-convert
    WT8 p;
    for (int L = 0; L < 4; ++L) {
        p.src[L * 2] = w[L][0];     p.dst[L * 2] = wt[L][0];
        p.K[L * 2] = dims_in[L];    p.N[L * 2] = dims_h[L];
        p.src[L * 2 + 1] = w[L][1]; p.dst[L * 2 + 1] = wt[L][1];
        p.K[L * 2 + 1] = dims_h[L]; p.N[L * 2 + 1] = dims_h[L];
    }
    wtconv_kernel<<<dim3(256, 8), 256, 0, stream>>>(p);

    // ---- CSR build ----
    hipMemsetAsync(deg, 0, (size_t)N_NODES * 4, stream);
    bucket_count_kernel<<<PART_B, 256, 0, stream>>>(dst, deg, cnt);
    scan_reduce_kernel<<<K_BUCK, 256, 0, stream>>>(cnt, bsum2, K_BUCK * PART_B);
    scan_bsum_kernel<<<1, 256, 0, stream>>>(bsum2, K_BUCK);
    scan_apply_kernel<<<K_BUCK, 256, 0, stream>>>(cnt, bsum2, cnt, K_BUCK * PART_B);
    partition_kernel<<<PART_B, 256, 0, stream>>>(src, dst, cnt, P);
    fine_scatter_kernel<<<K_BUCK, 256, 0, stream>>>(P, cnt, deg, rowptr, col);

    const int gx = (N_NODES + 127) / 128;       // 391
    const int gxp = ((gx + 7) / 8) * 8;         // 392
    const int gx64 = (N_NODES + 63) / 64;       // 782
    const int M = N_NODES;

    // ---- L1: G1 (fp32 x, 256->128 raw), agg@128+bias+relu, G2 (128->128 BN) ----
    mfma_gemm2_kernel<8, true, false><<<gxp, 256, 0, stream>>>(
        x, wt[0][0], nullptr, bufA, M, 256, 128, 2, gx, 1,
        nullptr, nullptr, nullptr, nullptr, nullptr, nullptr, nullptr);
    aggregate_bf16_kernel<16, true><<<(N_NODES + 15) / 16, 256, 0, stream>>>(
        bufA, rowptr, col, b[0][0], bufB, N_NODES);
    mfma_gemm2_kernel<8, false, false><<<gxp, 256, 0, stream>>>(
        bufB, wt[0][1], b[0][1], bufC, M, 128, 128, 1, gx, 1,
        bng[0], bnb[0], bnm[0], bnv[0], nullptr, nullptr, nullptr);

    // ---- L2: agg@128, fused MLP (128->256 relu -> 256 BN+relu) ----
    aggregate_bf16_kernel<16, false><<<(N_NODES + 15) / 16, 256, 0, stream>>>(
        bufC, rowptr, col, nullptr, bufA, N_NODES);
    fused_mlp_kernel<128, 256, 256><<<gx64, 256, 0, stream>>>(
        bufA, wt[1][0], wt[1][1],
        0, b[1][0], nullptr, nullptr, nullptr, nullptr,
        1, b[1][1], bng[1], bnb[1], bnm[1], bnv[1],
        bufC, M);

    // ---- L3: G1 (256->128 raw), agg@128+bias+relu ----
    mfma_gemm2_kernel<8, false, false><<<gxp, 256, 0, stream>>>(
        bufC, wt[2][0], nullptr, bufA, M, 256, 128, 2, gx, 1,
        nullptr, nullptr, nullptr, nullptr, nullptr, nullptr, nullptr);
    aggregate_bf16_kernel<16, true><<<(N_NODES + 15) / 16, 256, 0, stream>>>(
        bufA, rowptr, col, b[2][0], bufB, N_NODES);

    // ---- fused: L3 G2 (128->128 BN+relu) -> L4 G1 (128->64 raw) ----
    fused_mlp_kernel<128, 128, 64><<<gx64, 256, 0, stream>>>(
        bufB, wt[2][1], wt[3][0],
        1, b[2][1], bng[2], bnb[2], bnm[2], bnv[2],
        2, nullptr, nullptr, nullptr, nullptr, nullptr,
        bufA, M);

    // ---- L4: agg@64+bias+relu, G2+classifier ----
    aggregate_bf16_kernel<8, true><<<(N_NODES + 31) / 32, 256, 0, stream>>>(
        bufA, rowptr, col, b[3][0], bufB, N_NODES);
    mfma_gemm2_kernel<4, false, true><<<gxp, 256, 0, stream>>>(
        bufB, wt[3][1], b[3][1], nullptr, M, 64, 64, 1, gx, 1,
        bng[3], bnb[3], bnm[3], bnv[3], wc, bc, out);
}

// Round 11
// 485.093 us; speedup vs baseline: 1.0712x; 1.0712x over previous
//
#include <hip/hip_runtime.h>

#define N_NODES 50000
#define N_EDGES 800000
#define BN_EPS 1e-5f
#define K_BUCK 196        // dst >> 8 buckets (256 nodes each)
#define PART_B 256        // partition blocks
#define CHUNK 3125        // N_EDGES / PART_B

typedef __attribute__((ext_vector_type(8))) short bshort8;
typedef __attribute__((ext_vector_type(4))) float f32x4;

__device__ inline float bf2f(unsigned int u16) {
    return __uint_as_float(u16 << 16);
}
__device__ inline unsigned short f2bf(float f) {
    unsigned int u = __float_as_uint(f);
    u = (u + 0x7FFFu + ((u >> 16) & 1u)) >> 16;
    return (unsigned short)u;
}

// ---------------- scan helpers ----------------

__device__ inline int block_exscan256(int v, int tid, int* total) {
    int lane = tid & 63;
    int wave = tid >> 6;
    int incl = v;
#pragma unroll
    for (int off = 1; off < 64; off <<= 1) {
        int t = __shfl_up(incl, off, 64);
        if (lane >= off) incl += t;
    }
    __shared__ int wsum[4];
    if (lane == 63) wsum[wave] = incl;
    __syncthreads();
    int w0 = wsum[0], w1 = wsum[1], w2 = wsum[2], w3 = wsum[3];
    __syncthreads();
    int wofs = (wave > 0 ? w0 : 0) + (wave > 1 ? w1 : 0) + (wave > 2 ? w2 : 0);
    *total = w0 + w1 + w2 + w3;
    return wofs + incl - v;
}

__global__ __launch_bounds__(256) void scan_reduce_kernel(const int* __restrict__ in,
                                                          int* __restrict__ bsum, int n) {
    int tid = threadIdx.x;
    int i = blockIdx.x * 256 + tid;
    int v = (i < n) ? in[i] : 0;
    int lane = tid & 63;
    int wave = tid >> 6;
#pragma unroll
    for (int off = 32; off > 0; off >>= 1) v += __shfl_down(v, off, 64);
    __shared__ int wsum[4];
    if (lane == 0) wsum[wave] = v;
    __syncthreads();
    if (tid == 0) bsum[blockIdx.x] = wsum[0] + wsum[1] + wsum[2] + wsum[3];
}

__global__ __launch_bounds__(256) void scan_bsum_kernel(int* __restrict__ bsum, int B) {
    int tid = threadIdx.x;
    int v = (tid < B) ? bsum[tid] : 0;
    int total;
    int excl = block_exscan256(v, tid, &total);
    if (tid < B) bsum[tid] = excl;
}

__global__ __launch_bounds__(256) void scan_apply_kernel(const int* __restrict__ in,
                                                         const int* __restrict__ bsum,
                                                         int* __restrict__ out, int n) {
    int tid = threadIdx.x;
    int i = blockIdx.x * 256 + tid;
    int v = (i < n) ? in[i] : 0;
    int total;
    int excl = block_exscan256(v, tid, &total);
    if (i < n) out[i] = bsum[blockIdx.x] + excl;
}

// ---- bucketed CSR build ----

__global__ __launch_bounds__(256) void bucket_count_kernel(const int* __restrict__ dst,
                                                           int* __restrict__ deg,
                                                           int* __restrict__ cnt) {
    __shared__ int lcnt[K_BUCK];
    int tid = threadIdx.x;
    for (int i = tid; i < K_BUCK; i += 256) lcnt[i] = 0;
    __syncthreads();
    int start = blockIdx.x * CHUNK;
    for (int it = tid; it < CHUNK; it += 256) {
        int d = dst[start + it];
        atomicAdd(&lcnt[d >> 8], 1);
        atomicAdd(&deg[d], 1);
    }
    __syncthreads();
    for (int i = tid; i < K_BUCK; i += 256) cnt[i * PART_B + blockIdx.x] = lcnt[i];
}

__global__ __launch_bounds__(256) void partition_kernel(const int* __restrict__ src,
                                                        const int* __restrict__ dst,
                                                        const int* __restrict__ base,
                                                        uint2* __restrict__ P) {
    __shared__ int lofs[K_BUCK];
    int tid = threadIdx.x;
    for (int i = tid; i < K_BUCK; i += 256) lofs[i] = base[i * PART_B + blockIdx.x];
    __syncthreads();
    int start = blockIdx.x * CHUNK;
    for (int it = tid; it < CHUNK; it += 256) {
        int e = start + it;
        int d = dst[e], s = src[e];
        int p = atomicAdd(&lofs[d >> 8], 1);
        P[p] = make_uint2((unsigned)d, (unsigned)s);
    }
}

__global__ __launch_bounds__(256) void fine_scatter_kernel(const uint2* __restrict__ P,
                                                           const int* __restrict__ base,
                                                           const int* __restrict__ deg,
                                                           int* __restrict__ rowptr,
                                                           int* __restrict__ col) {
    __shared__ int wloc[256];
    int b = blockIdx.x;
    int tid = threadIdx.x;
    int nbase = b << 8;
    int nn = min(256, N_NODES - nbase);
    int d = (tid < nn) ? deg[nbase + tid] : 0;
    int total;
    int excl = block_exscan256(d, tid, &total);
    int start = base[b * PART_B];
    int rp = start + excl;
    if (tid < nn) {
        rowptr[nbase + tid] = rp;
        wloc[tid] = rp;
    }
    if (b == K_BUCK - 1 && tid == 0) rowptr[N_NODES] = N_EDGES;
    __syncthreads();
    int end = (b + 1 < K_BUCK) ? base[(b + 1) * PART_B] : N_EDGES;
    for (int e = start + tid; e < end; e += 256) {
        uint2 pr = P[e];
        int rank = atomicAdd(&wloc[pr.x - nbase], 1);
        col[rank] = (int)pr.y;
    }
}

// ---------------- conversions ----------------

struct WT8 {
    const float* src[8];
    unsigned short* dst[8];
    int K[8];
    int N[8];
};

// W[K][N] fp32 -> Wt[N][K] bf16 (row-major transposed; for mfma_gemm2 LDS staging)
__global__ __launch_bounds__(256) void wtconv_kernel(WT8 p) {
    int wi = blockIdx.y;
    int K = p.K[wi], N = p.N[wi];
    int idx = blockIdx.x * 256 + threadIdx.x;
    if (idx >= K * N) return;
    int logn = 31 - __clz(N);
    int n = idx & (N - 1);
    int k = idx >> logn;
    p.dst[wi][(size_t)n * K + k] = f2bf(p.src[wi][idx]);
}

// W[K][N] fp32 -> Wp fragment-packed bf16: Wp[((t*S + s)*64 + lane)*8 + j]
//  = W[s*32 + (lane>>4)*8 + j][t*16 + (lane&15)]   (t = n-tile, s = k-tile)
// A wave's B-fragment load becomes one coalesced 1KB burst.
__global__ __launch_bounds__(256) void wpconv_kernel(WT8 p) {
    int wi = blockIdx.y;
    int K = p.K[wi], N = p.N[wi];
    int idx = blockIdx.x * 256 + threadIdx.x;
    if (idx >= K * N) return;
    int S = K >> 5;
    int logs = 31 - __clz(S);
    int j = idx & 7;
    int l = (idx >> 3) & 63;
    int rest = idx >> 9;
    int s = rest & (S - 1);
    int t = rest >> logs;
    int k = s * 32 + ((l >> 4) << 3) + j;
    int n = t * 16 + (l & 15);
    p.dst[wi][idx] = f2bf(p.src[wi][(size_t)k * N + n]);
}

// ---------------- aggregation (bf16) ----------------

__device__ inline void acc8(uint4 v, float* a) {
    a[0] += bf2f(v.x & 0xFFFFu); a[1] += __uint_as_float(v.x & 0xFFFF0000u);
    a[2] += bf2f(v.y & 0xFFFFu); a[3] += __uint_as_float(v.y & 0xFFFF0000u);
    a[4] += bf2f(v.z & 0xFFFFu); a[5] += __uint_as_float(v.z & 0xFFFF0000u);
    a[6] += bf2f(v.w & 0xFFFFu); a[7] += __uint_as_float(v.w & 0xFFFF0000u);
}

template <int LPN, bool RELU>
__global__ __launch_bounds__(256) void aggregate_bf16_kernel(
    const unsigned short* __restrict__ h, const int* __restrict__ rowptr,
    const int* __restrict__ col, const float* __restrict__ bias,
    unsigned short* __restrict__ z, int n) {
    const int gpb = 256 / LPN;
    int gid = threadIdx.x / LPN;
    int l = threadIdx.x % LPN;
    int node = blockIdx.x * gpb + gid;
    if (node >= n) return;
    const uint4* hv = (const uint4*)h;
    float a[8] = {};
    acc8(hv[(size_t)node * LPN + l], a);  // self
    int s = rowptr[node], epos = rowptr[node + 1];
    for (int e = s; e < epos; ++e) {
        int j = col[e];
        acc8(hv[(size_t)j * LPN + l], a);
    }
    if (RELU) {
        float4 b0 = *(const float4*)(bias + l * 8);
        float4 b1 = *(const float4*)(bias + l * 8 + 4);
        a[0] = fmaxf(a[0] + b0.x, 0.f); a[1] = fmaxf(a[1] + b0.y, 0.f);
        a[2] = fmaxf(a[2] + b0.z, 0.f); a[3] = fmaxf(a[3] + b0.w, 0.f);
        a[4] = fmaxf(a[4] + b1.x, 0.f); a[5] = fmaxf(a[5] + b1.y, 0.f);
        a[6] = fmaxf(a[6] + b1.z, 0.f); a[7] = fmaxf(a[7] + b1.w, 0.f);
    }
    uint4 o;
    o.x = (unsigned int)f2bf(a[0]) | ((unsigned int)f2bf(a[1]) << 16);
    o.y = (unsigned int)f2bf(a[2]) | ((unsigned int)f2bf(a[3]) << 16);
    o.z = (unsigned int)f2bf(a[4]) | ((unsigned int)f2bf(a[5]) << 16);
    o.w = (unsigned int)f2bf(a[6]) | ((unsigned int)f2bf(a[7]) << 16);
    ((uint4*)z)[(size_t)node * LPN + l] = o;
}

// ---------------- epilogue scale/shift helper ----------------

__device__ inline void epi_coeff(int mode, int c, const float* bias, const float* g,
                                 const float* be, const float* mu, const float* var,
                                 float* s, float* sh) {
    *s = 1.f; *sh = 0.f;
    if (mode == 0) {
        *sh = bias[c];
    } else if (mode == 1) {
        float t = g[c] * rsqrtf(var[c] + BN_EPS);
        *s = t;
        *sh = be[c] - mu[c] * t + bias[c] * t;
    }
}

// ---------------- bf16 MFMA GEMM v2 + XCD swizzle (+ optional fused classifier) ----

template <int NT, bool F32A, bool CLS>
__global__ __launch_bounds__(256) void mfma_gemm2_kernel(
    const void* __restrict__ Ain, const unsigned short* __restrict__ Wt,
    const float* __restrict__ bias, unsigned short* __restrict__ C,
    int M, int K, int Nn, int mode, int gxblocks, int gy,
    const float* __restrict__ g, const float* __restrict__ be,
    const float* __restrict__ mu, const float* __restrict__ var,
    const float* __restrict__ wcls, const float* __restrict__ bcls,
    float* __restrict__ outp) {
    constexpr int BM = 128, BK = 64;
    constexpr int BN = NT * 16;
    constexpr int LDA = BK + 8;
    constexpr int LDB = BK + 8;
    constexpr int LDE = BN + 8;
    constexpr int NB_LD = (BN * BK / 8) / 256;
    __shared__ __align__(16) unsigned short smem[BM * LDA + BN * LDB];
    unsigned short* As = smem;
    unsigned short* Bs = smem + BM * LDA;
    unsigned short* Ep = smem;

    int id = blockIdx.x;
    int lo = id & 7;
    int t = id >> 3;
    int y = t % gy;
    int x = ((t / gy) << 3) | lo;
    if (x >= gxblocks) return;

    const int tid = threadIdx.x;
    const int wv = tid >> 6;
    const int ln = tid & 63;
    const int l15 = ln & 15;
    const int quad = ln >> 4;
    const int row0 = x * BM;
    const int col0 = y * BN;

    const unsigned short* A16 = (const unsigned short*)Ain;
    const float* A32 = (const float*)Ain;

    uint4 Ar[4], Br[NB_LD];

    auto loadA = [&](int k0) {
#pragma unroll
        for (int u = 0; u < 4; ++u) {
            int idx2 = tid + 256 * u;
            int r = idx2 >> 3, cg = (idx2 & 7) * 8;
            int gr = row0 + r;
            if (gr >= M) gr = M - 1;
            if (F32A) {
                float4 f0 = *(const float4*)(A32 + (size_t)gr * K + k0 + cg);
                float4 f1 = *(const float4*)(A32 + (size_t)gr * K + k0 + cg + 4);
                uint4 o;
                o.x = (unsigned)f2bf(f0.x) | ((unsigned)f2bf(f0.y) << 16);
                o.y = (unsigned)f2bf(f0.z) | ((unsigned)f2bf(f0.w) << 16);
                o.z = (unsigned)f2bf(f1.x) | ((unsigned)f2bf(f1.y) << 16);
                o.w = (unsigned)f2bf(f1.z) | ((unsigned)f2bf(f1.w) << 16);
                Ar[u] = o;
            } else {
                Ar[u] = *(const uint4*)(A16 + (size_t)gr * K + k0 + cg);
            }
        }
    };
    auto loadB = [&](int k0) {
#pragma unroll
        for (int u = 0; u < NB_LD; ++u) {
            int idx2 = tid + 256 * u;
            int r = idx2 >> 3, cg = (idx2 & 7) * 8;
            Br[u] = *(const uint4*)(Wt + (size_t)(col0 + r) * K + k0 + cg);
        }
    };
    auto stage = [&]() {
#pragma unroll
        for (int u = 0; u < 4; ++u) {
            int idx2 = tid + 256 * u;
            int r = idx2 >> 3, cg = (idx2 & 7) * 8;
            *(uint4*)(&As[r * LDA + cg]) = Ar[u];
        }
#pragma unroll
        for (int u = 0; u < NB_LD; ++u) {
            int idx2 = tid + 256 * u;
            int r = idx2 >> 3, cg = (idx2 & 7) * 8;
            *(uint4*)(&Bs[r * LDB + cg]) = Br[u];
        }
    };

    f32x4 acc[2][NT] = {};
    const int KT = K >> 6;
    loadA(0);
    loadB(0);
    for (int kt = 0; kt < KT; ++kt) {
        if (kt > 0) __syncthreads();
        stage();
        __syncthreads();
        if (kt + 1 < KT) {
            loadA((kt + 1) * 64);
            loadB((kt + 1) * 64);
        }
#pragma unroll
        for (int kh = 0; kh < 2; ++kh) {
            bshort8 af[2];
#pragma unroll
            for (int mt = 0; mt < 2; ++mt)
                af[mt] = *(const bshort8*)(&As[(wv * 32 + mt * 16 + l15) * LDA + kh * 32 + quad * 8]);
#pragma unroll
            for (int nt = 0; nt < NT; ++nt) {
                bshort8 bf = *(const bshort8*)(&Bs[(nt * 16 + l15) * LDB + kh * 32 + quad * 8]);
                acc[0][nt] = __builtin_amdgcn_mfma_f32_16x16x32_bf16(af[0], bf, acc[0][nt], 0, 0, 0);
                acc[1][nt] = __builtin_amdgcn_mfma_f32_16x16x32_bf16(af[1], bf, acc[1][nt], 0, 0, 0);
            }
        }
    }

    __syncthreads();
#pragma unroll
    for (int nt = 0; nt < NT; ++nt) {
        int c = col0 + nt * 16 + l15;
        float s, sh;
        epi_coeff(mode, c, bias, g, be, mu, var, &s, &sh);
#pragma unroll
        for (int mt = 0; mt < 2; ++mt) {
            int rl = wv * 32 + mt * 16 + quad * 4;
#pragma unroll
            for (int r = 0; r < 4; ++r) {
                float v = acc[mt][nt][r] * s + sh;
                if (mode != 2) v = fmaxf(v, 0.f);
                Ep[(rl + r) * LDE + nt * 16 + l15] = f2bf(v);
            }
        }
    }
    __syncthreads();
    if (CLS) {
        int r = tid >> 1, j = tid & 1;
        int grow = row0 + r;
        if (grow < M) {
            float s = 0.f;
#pragma unroll 8
            for (int k = 0; k < 64; ++k)
                s += bf2f(Ep[r * LDE + k]) * wcls[k * 2 + j];
            outp[(size_t)grow * 2 + j] = s + bcls[j];
        }
    } else {
        constexpr int CGR = BN / 8;
        constexpr int NU = BM * CGR / 256;
#pragma unroll
        for (int u = 0; u < NU; ++u) {
            int idx2 = tid + 256 * u;
            int r = idx2 / CGR, cg = (idx2 % CGR) * 8;
            int grow = row0 + r;
            if (grow < M)
                *(uint4*)(C + (size_t)grow * Nn + col0 + cg) = *(const uint4*)(&Ep[r * LDE + cg]);
        }
    }
}

// ---------------- fused 2-stage MLP GEMM (packed-B, reg-pipelined) ----------------
// C = epi2( epi1(A @ W1) @ W2 ). B operands come from fragment-packed Wp arrays:
// one wave B-fragment load = one coalesced 1KB burst. __launch_bounds__(256,3)
// caps VGPR at ~170 so the compiler can keep prefetched fragments live (R10:
// default bounds made it sink the loads; VGPR stayed 76). Stage-2's first
// fragment set is hoisted to kernel start (no dependencies; values survive
// barriers). Stage-2 loop is barrier-free -> full depth-1 pipelining.

template <int KIN, int DH1, int DH2>
__global__ __launch_bounds__(256, 3) void fused_mlp_kernel(
    const unsigned short* __restrict__ A,
    const unsigned short* __restrict__ Wp1, const unsigned short* __restrict__ Wp2,
    int mode1, const float* __restrict__ b1, const float* __restrict__ g1,
    const float* __restrict__ be1, const float* __restrict__ mu1, const float* __restrict__ var1,
    int mode2, const float* __restrict__ b2, const float* __restrict__ g2,
    const float* __restrict__ be2, const float* __restrict__ mu2, const float* __restrict__ var2,
    unsigned short* __restrict__ C, int M) {
    constexpr int BM = 64, BK = 64;
    constexpr int LDA = BK + 8;
    constexpr int LT1 = DH1 + 8;
    constexpr int LDE = DH2 + 8;
    constexpr int NT1 = DH1 / 32;
    constexpr int NT2 = DH2 / 32;
    constexpr int KT = KIN / 64;
    constexpr int S1 = KIN / 32;   // stage-1 k-tiles (32 k each)
    constexpr int S2 = DH1 / 32;   // stage-2 k-tiles
    __shared__ __align__(16) unsigned short As[BM * LDA];
    __shared__ __align__(16) unsigned short T1[BM * LT1];   // reused as Ep

    const int tid = threadIdx.x;
    const int wv = tid >> 6;
    const int ln = tid & 63;
    const int l15 = ln & 15;
    const int quad = ln >> 4;
    const int rw = (wv >> 1) * 32;
    const int tb1 = (wv & 1) * (DH1 / 32);  // n-tile base, stage 1 (half width)
    const int tb2 = (wv & 1) * (DH2 / 32);
    const int ch1 = (wv & 1) * (DH1 / 2);
    const int ch2 = (wv & 1) * (DH2 / 2);
    const int row0 = blockIdx.x * BM;

    uint4 Ar[2];
    auto loadA = [&](int k0) {
#pragma unroll
        for (int u = 0; u < 2; ++u) {
            int idx2 = tid + 256 * u;
            int r = idx2 >> 3, cg = (idx2 & 7) * 8;
            int gr = row0 + r;
            if (gr >= M) gr = M - 1;
            Ar[u] = *(const uint4*)(A + (size_t)gr * KIN + k0 + cg);
        }
    };
    auto stageA = [&]() {
#pragma unroll
        for (int u = 0; u < 2; ++u) {
            int idx2 = tid + 256 * u;
            int r = idx2 >> 3, cg = (idx2 & 7) * 8;
            *(uint4*)(&As[r * LDA + cg]) = Ar[u];
        }
    };
    auto loadB1 = [&](int s, bshort8* d) {  // s = k-tile index
#pragma unroll
        for (int nt = 0; nt < NT1; ++nt)
            d[nt] = *(const bshort8*)(Wp1 + ((size_t)((tb1 + nt) * S1 + s) * 64 + ln) * 8);
    };
    auto loadB2 = [&](int s, bshort8* d) {
#pragma unroll
        for (int nt = 0; nt < NT2; ++nt)
            d[nt] = *(const bshort8*)(Wp2 + ((size_t)((tb2 + nt) * S2 + s) * 64 + ln) * 8);
    };

    // ---- stage 1 ----
    f32x4 acc1[2][NT1] = {};
    bshort8 bf[NT1], bnx[NT1], bf2[NT2];
    loadA(0);
    loadB1(0, bf);
    loadB2(0, bf2);  // hoisted stage-2 prefetch: no deps, survives barriers
    for (int kt = 0; kt < KT; ++kt) {
        if (kt > 0) __syncthreads();
        stageA();
        __syncthreads();
        if (kt + 1 < KT) loadA((kt + 1) * 64);
#pragma unroll
        for (int kh = 0; kh < 2; ++kh) {
            int st = kt * 2 + kh;
            if (st + 1 < S1) loadB1(st + 1, bnx);
            bshort8 af[2];
#pragma unroll
            for (int mt = 0; mt < 2; ++mt)
                af[mt] = *(const bshort8*)(&As[(rw + mt * 16 + l15) * LDA + kh * 32 + quad * 8]);
#pragma unroll
            for (int nt = 0; nt < NT1; ++nt) {
                acc1[0][nt] = __builtin_amdgcn_mfma_f32_16x16x32_bf16(af[0], bf[nt], acc1[0][nt], 0, 0, 0);
                acc1[1][nt] = __builtin_amdgcn_mfma_f32_16x16x32_bf16(af[1], bf[nt], acc1[1][nt], 0, 0, 0);
            }
            if (st + 1 < S1) {
#pragma unroll
                for (int nt = 0; nt < NT1; ++nt) bf[nt] = bnx[nt];
            }
        }
    }
    // epi1 -> T1 (LDS)
#pragma unroll
    for (int nt = 0; nt < NT1; ++nt) {
        int c = ch1 + nt * 16 + l15;
        float s, sh;
        epi_coeff(mode1, c, b1, g1, be1, mu1, var1, &s, &sh);
#pragma unroll
        for (int mt = 0; mt < 2; ++mt) {
            int rl = rw + mt * 16 + quad * 4;
#pragma unroll
            for (int r = 0; r < 4; ++r) {
                float v = acc1[mt][nt][r] * s + sh;
                if (mode1 != 2) v = fmaxf(v, 0.f);
                T1[(rl + r) * LT1 + c] = f2bf(v);
            }
        }
    }
    __syncthreads();

    // ---- stage 2: A from T1 (LDS), B depth-1 pipelined, no barriers in loop ----
    f32x4 acc2[2][NT2] = {};
    bshort8 bnx2[NT2];
#pragma unroll
    for (int ks = 0; ks < S2; ++ks) {
        if (ks + 1 < S2) loadB2(ks + 1, bnx2);
        bshort8 af[2];
#pragma unroll
        for (int mt = 0; mt < 2; ++mt)
            af[mt] = *(const bshort8*)(&T1[(rw + mt * 16 + l15) * LT1 + ks * 32 + quad * 8]);
#pragma unroll
        for (int nt = 0; nt < NT2; ++nt) {
            acc2[0][nt] = __builtin_amdgcn_mfma_f32_16x16x32_bf16(af[0], bf2[nt], acc2[0][nt], 0, 0, 0);
            acc2[1][nt] = __builtin_amdgcn_mfma_f32_16x16x32_bf16(af[1], bf2[nt], acc2[1][nt], 0, 0, 0);
        }
        if (ks + 1 < S2) {
#pragma unroll
            for (int nt = 0; nt < NT2; ++nt) bf2[nt] = bnx2[nt];
        }
    }
    __syncthreads();  // done reading T1; safe to overwrite as Ep

    unsigned short* Ep = T1;
#pragma unroll
    for (int nt = 0; nt < NT2; ++nt) {
        int c = ch2 + nt * 16 + l15;
        float s, sh;
        epi_coeff(mode2, c, b2, g2, be2, mu2, var2, &s, &sh);
#pragma unroll
        for (int mt = 0; mt < 2; ++mt) {
            int rl = rw + mt * 16 + quad * 4;
#pragma unroll
            for (int r = 0; r < 4; ++r) {
                float v = acc2[mt][nt][r] * s + sh;
                if (mode2 != 2) v = fmaxf(v, 0.f);
                Ep[(rl + r) * LDE + c] = f2bf(v);
            }
        }
    }
    __syncthreads();
    constexpr int CGR = DH2 / 8;
    constexpr int NU = BM * CGR / 256;
#pragma unroll
    for (int u = 0; u < NU; ++u) {
        int idx2 = tid + 256 * u;
        int r = idx2 / CGR, cg = (idx2 % CGR) * 8;
        int grow = row0 + r;
        if (grow < M)
            *(uint4*)(C + (size_t)grow * DH2 + cg) = *(const uint4*)(&Ep[r * LDE + cg]);
    }
}

// ---------------- launch ----------------

extern "C" void kernel_launch(void* const* d_in, const int* in_sizes, int n_in,
                              void* d_out, int out_size, void* d_ws, size_t ws_size,
                              hipStream_t stream) {
    const float* x = (const float*)d_in[0];
    const int* ei = (const int*)d_in[1];
    const int* src = ei;
    const int* dst = ei + N_EDGES;
    const float* w[4][2];
    const float* b[4][2];
    const float* bng[4];
    const float* bnb[4];
    const float* bnm[4];
    const float* bnv[4];
    int idx = 2;
    for (int i = 0; i < 4; ++i) {
        w[i][0] = (const float*)d_in[idx++];
        b[i][0] = (const float*)d_in[idx++];
        w[i][1] = (const float*)d_in[idx++];
        b[i][1] = (const float*)d_in[idx++];
        bng[i] = (const float*)d_in[idx++];
        bnb[i] = (const float*)d_in[idx++];
        bnm[i] = (const float*)d_in[idx++];
        bnv[i] = (const float*)d_in[idx++];
    }
    const float* wc = (const float*)d_in[idx++];
    const float* bc = (const float*)d_in[idx++];
    float* out = (float*)d_out;

    char* ws = (char*)d_ws;
    size_t off = 0;
    auto alloc = [&](size_t bytes) {
        char* p = ws + off;
        off = (off + bytes + 255) & ~(size_t)255;
        return p;
    };
    int* deg = (int*)alloc((size_t)N_NODES * 4);
    int* rowptr = (int*)alloc((size_t)(N_NODES + 1) * 4);
    int* cnt = (int*)alloc((size_t)K_BUCK * PART_B * 4);
    int* bsum2 = (int*)alloc((size_t)K_BUCK * 4);
    int* col = (int*)alloc((size_t)N_EDGES * 4);
    uint2* P = (uint2*)alloc((size_t)N_EDGES * 8);
    unsigned short* bufA = (unsigned short*)alloc((size_t)N_NODES * 256 * 2);
    unsigned short* bufB = (unsigned short*)alloc((size_t)N_NODES * 256 * 2);
    unsigned short* bufC = (unsigned short*)alloc((size_t)N_NODES * 256 * 2);
    const int dims_in[4] = {256, 128, 256, 128};
    const int dims_h[4] = {128, 256, 128, 64};
    unsigned short* wt[4][2];
    unsigned short* wp[4][2];
    for (int L = 0; L < 4; ++L) {
        wt[L][0] = (unsigned short*)alloc((size_t)dims_in[L] * dims_h[L] * 2);
        wt[L][1] = (unsigned short*)alloc((size_t)dims_h[L] * dims_h[L] * 2);
        wp[L][0] = (unsigned short*)alloc((size_t)dims_in[L] * dims_h[L] * 2);
        wp[L][1] = (unsigned short*)alloc((size_t)dims_h[L] * dims_h[L] * 2);
    }
    (void)ws_size;

    // weight conversions: row-major transposed (wt) + fragment-packed (wp)
    WT8 p;
    for (int L = 0; L < 4; ++L) {
        p.src[L * 2] = w[L][0];     p.dst[L * 2] = wt[L][0];
        p.K[L * 2] = dims_in[L];    p.N[L * 2] = dims_h[L];
        p.src[L * 2 + 1] = w[L][1]; p.dst[L * 2 + 1] = wt[L][1];
        p.K[L * 2 + 1] = dims_h[L]; p.N[L * 2 + 1] = dims_h[L];
    }
    wtconv_kernel<<<dim3(256, 8), 256, 0, stream>>>(p);
    WT8 q = p;
    for (int L = 0; L < 4; ++L) {
        q.dst[L * 2] = wp[L][0];
        q.dst[L * 2 + 1] = wp[L][1];
    }
    wpconv_kernel<<<dim3(256, 8), 256, 0, stream>>>(q);

    // ---- CSR build ----
    hipMemsetAsync(deg, 0, (size_t)N_NODES * 4, stream);
    bucket_count_kernel<<<PART_B, 256, 0, stream>>>(dst, deg, cnt);
    scan_reduce_kernel<<<K_BUCK, 256, 0, stream>>>(cnt, bsum2, K_BUCK * PART_B);
    scan_bsum_kernel<<<1, 256, 0, stream>>>(bsum2, K_BUCK);
    scan_apply_kernel<<<K_BUCK, 256, 0, stream>>>(cnt, bsum2, cnt, K_BUCK * PART_B);
    partition_kernel<<<PART_B, 256, 0, stream>>>(src, dst, cnt, P);
    fine_scatter_kernel<<<K_BUCK, 256, 0, stream>>>(P, cnt, deg, rowptr, col);

    const int gx = (N_NODES + 127) / 128;       // 391
    const int gxp = ((gx + 7) / 8) * 8;         // 392
    const int gx64 = (N_NODES + 63) / 64;       // 782
    const int M = N_NODES;

    // ---- L1: G1 (fp32 x, 256->128 raw), agg@128+bias+relu, G2 (128->128 BN) ----
    mfma_gemm2_kernel<8, true, false><<<gxp, 256, 0, stream>>>(
        x, wt[0][0], nullptr, bufA, M, 256, 128, 2, gx, 1,
        nullptr, nullptr, nullptr, nullptr, nullptr, nullptr, nullptr);
    aggregate_bf16_kernel<16, true><<<(N_NODES + 15) / 16, 256, 0, stream>>>(
        bufA, rowptr, col, b[0][0], bufB, N_NODES);
    mfma_gemm2_kernel<8, false, false><<<gxp, 256, 0, stream>>>(
        bufB, wt[0][1], b[0][1], bufC, M, 128, 128, 1, gx, 1,
        bng[0], bnb[0], bnm[0], bnv[0], nullptr, nullptr, nullptr);

    // ---- L2: agg@128, fused MLP (128->256 relu -> 256 BN+relu) ----
    aggregate_bf16_kernel<16, false><<<(N_NODES + 15) / 16, 256, 0, stream>>>(
        bufC, rowptr, col, nullptr, bufA, N_NODES);
    fused_mlp_kernel<128, 256, 256><<<gx64, 256, 0, stream>>>(
        bufA, wp[1][0], wp[1][1],
        0, b[1][0], nullptr, nullptr, nullptr, nullptr,
        1, b[1][1], bng[1], bnb[1], bnm[1], bnv[1],
        bufC, M);

    // ---- L3: G1 (256->128 raw), agg@128+bias+relu ----
    mfma_gemm2_kernel<8, false, false><<<gxp, 256, 0, stream>>>(
        bufC, wt[2][0], nullptr, bufA, M, 256, 128, 2, gx, 1,
        nullptr, nullptr, nullptr, nullptr, nullptr, nullptr, nullptr);
    aggregate_bf16_kernel<16, true><<<(N_NODES + 15) / 16, 256, 0, stream>>>(
        bufA, rowptr, col, b[2][0], bufB, N_NODES);

    // ---- fused: L3 G2 (128->128 BN+relu) -> L4 G1 (128->64 raw) ----
    fused_mlp_kernel<128, 128, 64><<<gx64, 256, 0, stream>>>(
        bufB, wp[2][1], wp[3][0],
        1, b[2][1], bng[2], bnb[2], bnm[2], bnv[2],
        2, nullptr, nullptr, nullptr, nullptr, nullptr,
        bufA, M);

    // ---- L4: agg@64+bias+relu, G2+classifier ----
    aggregate_bf16_kernel<8, true><<<(N_NODES + 31) / 32, 256, 0, stream>>>(
        bufA, rowptr, col, b[3][0], bufB, N_NODES);
    mfma_gemm2_kernel<4, false, true><<<gxp, 256, 0, stream>>>(
        bufB, wt[3][1], b[3][1], nullptr, M, 64, 64, 1, gx, 1,
        bng[3], bnb[3], bnm[3], bnv[3], wc, bc, out);
}

// Round 12
// 458.505 us; speedup vs baseline: 1.1333x; 1.0580x over previous
//
#include <hip/hip_runtime.h>

#define N_NODES 50000
#define N_EDGES 800000
#define BN_EPS 1e-5f
#define K_BUCK 196        // dst >> 8 buckets (256 nodes each)
#define PART_B 256        // partition blocks
#define CHUNK 3125        // N_EDGES / PART_B

typedef __attribute__((ext_vector_type(8))) short bshort8;
typedef __attribute__((ext_vector_type(4))) float f32x4;

__device__ inline float bf2f(unsigned int u16) {
    return __uint_as_float(u16 << 16);
}
__device__ inline unsigned short f2bf(float f) {
    unsigned int u = __float_as_uint(f);
    u = (u + 0x7FFFu + ((u >> 16) & 1u)) >> 16;
    return (unsigned short)u;
}

// ---------------- scan helpers ----------------

__device__ inline int block_exscan256(int v, int tid, int* total) {
    int lane = tid & 63;
    int wave = tid >> 6;
    int incl = v;
#pragma unroll
    for (int off = 1; off < 64; off <<= 1) {
        int t = __shfl_up(incl, off, 64);
        if (lane >= off) incl += t;
    }
    __shared__ int wsum[4];
    if (lane == 63) wsum[wave] = incl;
    __syncthreads();
    int w0 = wsum[0], w1 = wsum[1], w2 = wsum[2], w3 = wsum[3];
    __syncthreads();
    int wofs = (wave > 0 ? w0 : 0) + (wave > 1 ? w1 : 0) + (wave > 2 ? w2 : 0);
    *total = w0 + w1 + w2 + w3;
    return wofs + incl - v;
}

__global__ __launch_bounds__(256) void scan_reduce_kernel(const int* __restrict__ in,
                                                          int* __restrict__ bsum, int n) {
    int tid = threadIdx.x;
    int i = blockIdx.x * 256 + tid;
    int v = (i < n) ? in[i] : 0;
    int lane = tid & 63;
    int wave = tid >> 6;
#pragma unroll
    for (int off = 32; off > 0; off >>= 1) v += __shfl_down(v, off, 64);
    __shared__ int wsum[4];
    if (lane == 0) wsum[wave] = v;
    __syncthreads();
    if (tid == 0) bsum[blockIdx.x] = wsum[0] + wsum[1] + wsum[2] + wsum[3];
}

__global__ __launch_bounds__(256) void scan_bsum_kernel(int* __restrict__ bsum, int B) {
    int tid = threadIdx.x;
    int v = (tid < B) ? bsum[tid] : 0;
    int total;
    int excl = block_exscan256(v, tid, &total);
    if (tid < B) bsum[tid] = excl;
}

__global__ __launch_bounds__(256) void scan_apply_kernel(const int* __restrict__ in,
                                                         const int* __restrict__ bsum,
                                                         int* __restrict__ out, int n) {
    int tid = threadIdx.x;
    int i = blockIdx.x * 256 + tid;
    int v = (i < n) ? in[i] : 0;
    int total;
    int excl = block_exscan256(v, tid, &total);
    if (i < n) out[i] = bsum[blockIdx.x] + excl;
}

// ---- bucketed CSR build ----

__global__ __launch_bounds__(256) void bucket_count_kernel(const int* __restrict__ dst,
                                                           int* __restrict__ deg,
                                                           int* __restrict__ cnt) {
    __shared__ int lcnt[K_BUCK];
    int tid = threadIdx.x;
    for (int i = tid; i < K_BUCK; i += 256) lcnt[i] = 0;
    __syncthreads();
    int start = blockIdx.x * CHUNK;
    for (int it = tid; it < CHUNK; it += 256) {
        int d = dst[start + it];
        atomicAdd(&lcnt[d >> 8], 1);
        atomicAdd(&deg[d], 1);
    }
    __syncthreads();
    for (int i = tid; i < K_BUCK; i += 256) cnt[i * PART_B + blockIdx.x] = lcnt[i];
}

__global__ __launch_bounds__(256) void partition_kernel(const int* __restrict__ src,
                                                        const int* __restrict__ dst,
                                                        const int* __restrict__ base,
                                                        uint2* __restrict__ P) {
    __shared__ int lofs[K_BUCK];
    int tid = threadIdx.x;
    for (int i = tid; i < K_BUCK; i += 256) lofs[i] = base[i * PART_B + blockIdx.x];
    __syncthreads();
    int start = blockIdx.x * CHUNK;
    for (int it = tid; it < CHUNK; it += 256) {
        int e = start + it;
        int d = dst[e], s = src[e];
        int p = atomicAdd(&lofs[d >> 8], 1);
        P[p] = make_uint2((unsigned)d, (unsigned)s);
    }
}

__global__ __launch_bounds__(256) void fine_scatter_kernel(const uint2* __restrict__ P,
                                                           const int* __restrict__ base,
                                                           const int* __restrict__ deg,
                                                           int* __restrict__ rowptr,
                                                           int* __restrict__ col) {
    __shared__ int wloc[256];
    int b = blockIdx.x;
    int tid = threadIdx.x;
    int nbase = b << 8;
    int nn = min(256, N_NODES - nbase);
    int d = (tid < nn) ? deg[nbase + tid] : 0;
    int total;
    int excl = block_exscan256(d, tid, &total);
    int start = base[b * PART_B];
    int rp = start + excl;
    if (tid < nn) {
        rowptr[nbase + tid] = rp;
        wloc[tid] = rp;
    }
    if (b == K_BUCK - 1 && tid == 0) rowptr[N_NODES] = N_EDGES;
    __syncthreads();
    int end = (b + 1 < K_BUCK) ? base[(b + 1) * PART_B] : N_EDGES;
    for (int e = start + tid; e < end; e += 256) {
        uint2 pr = P[e];
        int rank = atomicAdd(&wloc[pr.x - nbase], 1);
        col[rank] = (int)pr.y;
    }
}

// ---------------- conversions ----------------

struct WT8 {
    const float* src[8];
    unsigned short* dst[8];
    int K[8];
    int N[8];
};

// W[K][N] fp32 -> Wt[N][K] bf16 (row-major transposed; for mfma_gemm2 LDS staging)
__global__ __launch_bounds__(256) void wtconv_kernel(WT8 p) {
    int wi = blockIdx.y;
    int K = p.K[wi], N = p.N[wi];
    int idx = blockIdx.x * 256 + threadIdx.x;
    if (idx >= K * N) return;
    int logn = 31 - __clz(N);
    int n = idx & (N - 1);
    int k = idx >> logn;
    p.dst[wi][(size_t)n * K + k] = f2bf(p.src[wi][idx]);
}

// W[K][N] fp32 -> Wp fragment-packed bf16: Wp[((t*S + s)*64 + lane)*8 + j]
//  = W[s*32 + (lane>>4)*8 + j][t*16 + (lane&15)]   (t = n-tile, s = k-tile)
__global__ __launch_bounds__(256) void wpconv_kernel(WT8 p) {
    int wi = blockIdx.y;
    int K = p.K[wi], N = p.N[wi];
    int idx = blockIdx.x * 256 + threadIdx.x;
    if (idx >= K * N) return;
    int S = K >> 5;
    int logs = 31 - __clz(S);
    int j = idx & 7;
    int l = (idx >> 3) & 63;
    int rest = idx >> 9;
    int s = rest & (S - 1);
    int t = rest >> logs;
    int k = s * 32 + ((l >> 4) << 3) + j;
    int n = t * 16 + (l & 15);
    p.dst[wi][idx] = f2bf(p.src[wi][(size_t)k * N + n]);
}

// ---------------- aggregation (bf16) ----------------

__device__ inline void acc8(uint4 v, float* a) {
    a[0] += bf2f(v.x & 0xFFFFu); a[1] += __uint_as_float(v.x & 0xFFFF0000u);
    a[2] += bf2f(v.y & 0xFFFFu); a[3] += __uint_as_float(v.y & 0xFFFF0000u);
    a[4] += bf2f(v.z & 0xFFFFu); a[5] += __uint_as_float(v.z & 0xFFFF0000u);
    a[6] += bf2f(v.w & 0xFFFFu); a[7] += __uint_as_float(v.w & 0xFFFF0000u);
}

template <int LPN, bool RELU>
__global__ __launch_bounds__(256) void aggregate_bf16_kernel(
    const unsigned short* __restrict__ h, const int* __restrict__ rowptr,
    const int* __restrict__ col, const float* __restrict__ bias,
    unsigned short* __restrict__ z, int n) {
    const int gpb = 256 / LPN;
    int gid = threadIdx.x / LPN;
    int l = threadIdx.x % LPN;
    int node = blockIdx.x * gpb + gid;
    if (node >= n) return;
    const uint4* hv = (const uint4*)h;
    float a[8] = {};
    acc8(hv[(size_t)node * LPN + l], a);  // self
    int s = rowptr[node], epos = rowptr[node + 1];
    for (int e = s; e < epos; ++e) {
        int j = col[e];
        acc8(hv[(size_t)j * LPN + l], a);
    }
    if (RELU) {
        float4 b0 = *(const float4*)(bias + l * 8);
        float4 b1 = *(const float4*)(bias + l * 8 + 4);
        a[0] = fmaxf(a[0] + b0.x, 0.f); a[1] = fmaxf(a[1] + b0.y, 0.f);
        a[2] = fmaxf(a[2] + b0.z, 0.f); a[3] = fmaxf(a[3] + b0.w, 0.f);
        a[4] = fmaxf(a[4] + b1.x, 0.f); a[5] = fmaxf(a[5] + b1.y, 0.f);
        a[6] = fmaxf(a[6] + b1.z, 0.f); a[7] = fmaxf(a[7] + b1.w, 0.f);
    }
    uint4 o;
    o.x = (unsigned int)f2bf(a[0]) | ((unsigned int)f2bf(a[1]) << 16);
    o.y = (unsigned int)f2bf(a[2]) | ((unsigned int)f2bf(a[3]) << 16);
    o.z = (unsigned int)f2bf(a[4]) | ((unsigned int)f2bf(a[5]) << 16);
    o.w = (unsigned int)f2bf(a[6]) | ((unsigned int)f2bf(a[7]) << 16);
    ((uint4*)z)[(size_t)node * LPN + l] = o;
}

// ---------------- epilogue scale/shift helper ----------------

__device__ inline void epi_coeff(int mode, int c, const float* bias, const float* g,
                                 const float* be, const float* mu, const float* var,
                                 float* s, float* sh) {
    *s = 1.f; *sh = 0.f;
    if (mode == 0) {
        *sh = bias[c];
    } else if (mode == 1) {
        float t = g[c] * rsqrtf(var[c] + BN_EPS);
        *s = t;
        *sh = be[c] - mu[c] * t + bias[c] * t;
    }
}

// ---------------- bf16 MFMA GEMM v2 (LDS-B; used for F32A input + classifier tail) ----

template <int NT, bool F32A, bool CLS>
__global__ __launch_bounds__(256) void mfma_gemm2_kernel(
    const void* __restrict__ Ain, const unsigned short* __restrict__ Wt,
    const float* __restrict__ bias, unsigned short* __restrict__ C,
    int M, int K, int Nn, int mode, int gxblocks, int gy,
    const float* __restrict__ g, const float* __restrict__ be,
    const float* __restrict__ mu, const float* __restrict__ var,
    const float* __restrict__ wcls, const float* __restrict__ bcls,
    float* __restrict__ outp) {
    constexpr int BM = 128, BK = 64;
    constexpr int BN = NT * 16;
    constexpr int LDA = BK + 8;
    constexpr int LDB = BK + 8;
    constexpr int LDE = BN + 8;
    constexpr int NB_LD = (BN * BK / 8) / 256;
    __shared__ __align__(16) unsigned short smem[BM * LDA + BN * LDB];
    unsigned short* As = smem;
    unsigned short* Bs = smem + BM * LDA;
    unsigned short* Ep = smem;

    int id = blockIdx.x;
    int lo = id & 7;
    int t = id >> 3;
    int y = t % gy;
    int x = ((t / gy) << 3) | lo;
    if (x >= gxblocks) return;

    const int tid = threadIdx.x;
    const int wv = tid >> 6;
    const int ln = tid & 63;
    const int l15 = ln & 15;
    const int quad = ln >> 4;
    const int row0 = x * BM;
    const int col0 = y * BN;

    const unsigned short* A16 = (const unsigned short*)Ain;
    const float* A32 = (const float*)Ain;

    uint4 Ar[4], Br[NB_LD];

    auto loadA = [&](int k0) {
#pragma unroll
        for (int u = 0; u < 4; ++u) {
            int idx2 = tid + 256 * u;
            int r = idx2 >> 3, cg = (idx2 & 7) * 8;
            int gr = row0 + r;
            if (gr >= M) gr = M - 1;
            if (F32A) {
                float4 f0 = *(const float4*)(A32 + (size_t)gr * K + k0 + cg);
                float4 f1 = *(const float4*)(A32 + (size_t)gr * K + k0 + cg + 4);
                uint4 o;
                o.x = (unsigned)f2bf(f0.x) | ((unsigned)f2bf(f0.y) << 16);
                o.y = (unsigned)f2bf(f0.z) | ((unsigned)f2bf(f0.w) << 16);
                o.z = (unsigned)f2bf(f1.x) | ((unsigned)f2bf(f1.y) << 16);
                o.w = (unsigned)f2bf(f1.z) | ((unsigned)f2bf(f1.w) << 16);
                Ar[u] = o;
            } else {
                Ar[u] = *(const uint4*)(A16 + (size_t)gr * K + k0 + cg);
            }
        }
    };
    auto loadB = [&](int k0) {
#pragma unroll
        for (int u = 0; u < NB_LD; ++u) {
            int idx2 = tid + 256 * u;
            int r = idx2 >> 3, cg = (idx2 & 7) * 8;
            Br[u] = *(const uint4*)(Wt + (size_t)(col0 + r) * K + k0 + cg);
        }
    };
    auto stage = [&]() {
#pragma unroll
        for (int u = 0; u < 4; ++u) {
            int idx2 = tid + 256 * u;
            int r = idx2 >> 3, cg = (idx2 & 7) * 8;
            *(uint4*)(&As[r * LDA + cg]) = Ar[u];
        }
#pragma unroll
        for (int u = 0; u < NB_LD; ++u) {
            int idx2 = tid + 256 * u;
            int r = idx2 >> 3, cg = (idx2 & 7) * 8;
            *(uint4*)(&Bs[r * LDB + cg]) = Br[u];
        }
    };

    f32x4 acc[2][NT] = {};
    const int KT = K >> 6;
    loadA(0);
    loadB(0);
    for (int kt = 0; kt < KT; ++kt) {
        if (kt > 0) __syncthreads();
        stage();
        __syncthreads();
        if (kt + 1 < KT) {
            loadA((kt + 1) * 64);
            loadB((kt + 1) * 64);
        }
#pragma unroll
        for (int kh = 0; kh < 2; ++kh) {
            bshort8 af[2];
#pragma unroll
            for (int mt = 0; mt < 2; ++mt)
                af[mt] = *(const bshort8*)(&As[(wv * 32 + mt * 16 + l15) * LDA + kh * 32 + quad * 8]);
#pragma unroll
            for (int nt = 0; nt < NT; ++nt) {
                bshort8 bf = *(const bshort8*)(&Bs[(nt * 16 + l15) * LDB + kh * 32 + quad * 8]);
                acc[0][nt] = __builtin_amdgcn_mfma_f32_16x16x32_bf16(af[0], bf, acc[0][nt], 0, 0, 0);
                acc[1][nt] = __builtin_amdgcn_mfma_f32_16x16x32_bf16(af[1], bf, acc[1][nt], 0, 0, 0);
            }
        }
    }

    __syncthreads();
#pragma unroll
    for (int nt = 0; nt < NT; ++nt) {
        int c = col0 + nt * 16 + l15;
        float s, sh;
        epi_coeff(mode, c, bias, g, be, mu, var, &s, &sh);
#pragma unroll
        for (int mt = 0; mt < 2; ++mt) {
            int rl = wv * 32 + mt * 16 + quad * 4;
#pragma unroll
            for (int r = 0; r < 4; ++r) {
                float v = acc[mt][nt][r] * s + sh;
                if (mode != 2) v = fmaxf(v, 0.f);
                Ep[(rl + r) * LDE + nt * 16 + l15] = f2bf(v);
            }
        }
    }
    __syncthreads();
    if (CLS) {
        int r = tid >> 1, j = tid & 1;
        int grow = row0 + r;
        if (grow < M) {
            float s = 0.f;
#pragma unroll 8
            for (int k = 0; k < 64; ++k)
                s += bf2f(Ep[r * LDE + k]) * wcls[k * 2 + j];
            outp[(size_t)grow * 2 + j] = s + bcls[j];
        }
    } else {
        constexpr int CGR = BN / 8;
        constexpr int NU = BM * CGR / 256;
#pragma unroll
        for (int u = 0; u < NU; ++u) {
            int idx2 = tid + 256 * u;
            int r = idx2 / CGR, cg = (idx2 % CGR) * 8;
            int grow = row0 + r;
            if (grow < M)
                *(uint4*)(C + (size_t)grow * Nn + col0 + cg) = *(const uint4*)(&Ep[r * LDE + cg]);
        }
    }
}

// ---------------- packed-B single GEMM (retiled: wave = 64 rows x DH/4 cols) ----
// C = epi(A @ W). Zero B duplication across waves; 4 m-tiles per B fragment.
// LDS overlay: As (stage) and Ep (epilogue) share one buffer (barrier-separated).

template <int KIN, int DH>
__global__ __launch_bounds__(256, 4) void packed_gemm_kernel(
    const unsigned short* __restrict__ A, const unsigned short* __restrict__ Wp,
    int mode, const float* __restrict__ bias, const float* __restrict__ g,
    const float* __restrict__ be, const float* __restrict__ mu, const float* __restrict__ var,
    unsigned short* __restrict__ C, int M) {
    constexpr int BM = 64, BK = 64;
    constexpr int LDA = BK + 8;
    constexpr int LDE = DH + 8;
    constexpr int NT = DH / 64;   // n-tiles per wave (quarter width)
    constexpr int KT = KIN / 64;
    constexpr int S = KIN / 32;
    __shared__ __align__(16) unsigned short smem[BM * LDE];  // LDE >= LDA for DH>=64
    unsigned short* As = smem;
    unsigned short* Ep = smem;

    const int tid = threadIdx.x;
    const int wv = tid >> 6;
    const int ln = tid & 63;
    const int l15 = ln & 15;
    const int quad = ln >> 4;
    const int tb = wv * NT;
    const int ch = wv * (DH / 4);
    const int row0 = blockIdx.x * BM;

    uint4 Ar[2];
    auto loadA = [&](int k0) {
#pragma unroll
        for (int u = 0; u < 2; ++u) {
            int idx2 = tid + 256 * u;
            int r = idx2 >> 3, cg = (idx2 & 7) * 8;
            int gr = row0 + r;
            if (gr >= M) gr = M - 1;
            Ar[u] = *(const uint4*)(A + (size_t)gr * KIN + k0 + cg);
        }
    };
    auto stageA = [&]() {
#pragma unroll
        for (int u = 0; u < 2; ++u) {
            int idx2 = tid + 256 * u;
            int r = idx2 >> 3, cg = (idx2 & 7) * 8;
            *(uint4*)(&As[r * LDA + cg]) = Ar[u];
        }
    };
    auto loadB = [&](int s, bshort8* d) {
#pragma unroll
        for (int nt = 0; nt < NT; ++nt)
            d[nt] = *(const bshort8*)(Wp + ((size_t)((tb + nt) * S + s) * 64 + ln) * 8);
    };

    f32x4 acc[4][NT] = {};
    bshort8 bf[NT], bnx[NT];
    loadA(0);
    loadB(0, bf);
    for (int kt = 0; kt < KT; ++kt) {
        if (kt > 0) __syncthreads();
        stageA();
        __syncthreads();
        if (kt + 1 < KT) loadA((kt + 1) * 64);
#pragma unroll
        for (int kh = 0; kh < 2; ++kh) {
            int st = kt * 2 + kh;
            if (st + 1 < S) loadB(st + 1, bnx);
            bshort8 af[4];
#pragma unroll
            for (int mt = 0; mt < 4; ++mt)
                af[mt] = *(const bshort8*)(&As[(mt * 16 + l15) * LDA + kh * 32 + quad * 8]);
#pragma unroll
            for (int nt = 0; nt < NT; ++nt)
#pragma unroll
                for (int mt = 0; mt < 4; ++mt)
                    acc[mt][nt] = __builtin_amdgcn_mfma_f32_16x16x32_bf16(af[mt], bf[nt], acc[mt][nt], 0, 0, 0);
            if (st + 1 < S) {
#pragma unroll
                for (int nt = 0; nt < NT; ++nt) bf[nt] = bnx[nt];
            }
        }
    }
    __syncthreads();  // all As reads done before Ep overlay write
#pragma unroll
    for (int nt = 0; nt < NT; ++nt) {
        int c = ch + nt * 16 + l15;
        float s, sh;
        epi_coeff(mode, c, bias, g, be, mu, var, &s, &sh);
#pragma unroll
        for (int mt = 0; mt < 4; ++mt) {
            int rl = mt * 16 + quad * 4;
#pragma unroll
            for (int r = 0; r < 4; ++r) {
                float v = acc[mt][nt][r] * s + sh;
                if (mode != 2) v = fmaxf(v, 0.f);
                Ep[(rl + r) * LDE + c] = f2bf(v);
            }
        }
    }
    __syncthreads();
    constexpr int CGR = DH / 8;
    constexpr int NU = BM * CGR / 256;
#pragma unroll
    for (int u = 0; u < NU; ++u) {
        int idx2 = tid + 256 * u;
        int r = idx2 / CGR, cg = (idx2 % CGR) * 8;
        int grow = row0 + r;
        if (grow < M)
            *(uint4*)(C + (size_t)grow * DH + cg) = *(const uint4*)(&Ep[r * LDE + cg]);
    }
}

// ---------------- fused 2-stage MLP (retiled, packed-B, LDS overlay) ----------------
// C = epi2( epi1(A @ W1) @ W2 ). Wave = 64 rows x quarter cols both stages:
// no B duplication, 4 m-tiles of compute per B-fragment set. As/T1/Ep overlay.

template <int KIN, int DH1, int DH2>
__global__ __launch_bounds__(256, 3) void fused_mlp_kernel(
    const unsigned short* __restrict__ A,
    const unsigned short* __restrict__ Wp1, const unsigned short* __restrict__ Wp2,
    int mode1, const float* __restrict__ b1, const float* __restrict__ g1,
    const float* __restrict__ be1, const float* __restrict__ mu1, const float* __restrict__ var1,
    int mode2, const float* __restrict__ b2, const float* __restrict__ g2,
    const float* __restrict__ be2, const float* __restrict__ mu2, const float* __restrict__ var2,
    unsigned short* __restrict__ C, int M) {
    constexpr int BM = 64, BK = 64;
    constexpr int LDA = BK + 8;
    constexpr int LT1 = DH1 + 8;
    constexpr int LDE = DH2 + 8;
    constexpr int NT1 = DH1 / 64;
    constexpr int NT2 = DH2 / 64;
    constexpr int KT = KIN / 64;
    constexpr int S1 = KIN / 32;
    constexpr int S2 = DH1 / 32;
    __shared__ __align__(16) unsigned short smem[BM * LT1];  // As | T1 | Ep overlay
    unsigned short* As = smem;
    unsigned short* T1 = smem;

    const int tid = threadIdx.x;
    const int wv = tid >> 6;
    const int ln = tid & 63;
    const int l15 = ln & 15;
    const int quad = ln >> 4;
    const int tb1 = wv * NT1;
    const int tb2 = wv * NT2;
    const int ch1 = wv * (DH1 / 4);
    const int ch2 = wv * (DH2 / 4);
    const int row0 = blockIdx.x * BM;

    uint4 Ar[2];
    auto loadA = [&](int k0) {
#pragma unroll
        for (int u = 0; u < 2; ++u) {
            int idx2 = tid + 256 * u;
            int r = idx2 >> 3, cg = (idx2 & 7) * 8;
            int gr = row0 + r;
            if (gr >= M) gr = M - 1;
            Ar[u] = *(const uint4*)(A + (size_t)gr * KIN + k0 + cg);
        }
    };
    auto stageA = [&]() {
#pragma unroll
        for (int u = 0; u < 2; ++u) {
            int idx2 = tid + 256 * u;
            int r = idx2 >> 3, cg = (idx2 & 7) * 8;
            *(uint4*)(&As[r * LDA + cg]) = Ar[u];
        }
    };
    auto loadB1 = [&](int s, bshort8* d) {
#pragma unroll
        for (int nt = 0; nt < NT1; ++nt)
            d[nt] = *(const bshort8*)(Wp1 + ((size_t)((tb1 + nt) * S1 + s) * 64 + ln) * 8);
    };
    auto loadB2 = [&](int s, bshort8* d) {
#pragma unroll
        for (int nt = 0; nt < NT2; ++nt)
            d[nt] = *(const bshort8*)(Wp2 + ((size_t)((tb2 + nt) * S2 + s) * 64 + ln) * 8);
    };

    // ---- stage 1 ----
    f32x4 acc1[4][NT1] = {};
    bshort8 bf[NT1], bnx[NT1], bf2[NT2];
    loadA(0);
    loadB1(0, bf);
    loadB2(0, bf2);  // hoisted stage-2 prefetch (no deps; survives barriers)
    for (int kt = 0; kt < KT; ++kt) {
        if (kt > 0) __syncthreads();
        stageA();
        __syncthreads();
        if (kt + 1 < KT) loadA((kt + 1) * 64);
#pragma unroll
        for (int kh = 0; kh < 2; ++kh) {
            int st = kt * 2 + kh;
            if (st + 1 < S1) loadB1(st + 1, bnx);
            bshort8 af[4];
#pragma unroll
            for (int mt = 0; mt < 4; ++mt)
                af[mt] = *(const bshort8*)(&As[(mt * 16 + l15) * LDA + kh * 32 + quad * 8]);
#pragma unroll
            for (int nt = 0; nt < NT1; ++nt)
#pragma unroll
                for (int mt = 0; mt < 4; ++mt)
                    acc1[mt][nt] = __builtin_amdgcn_mfma_f32_16x16x32_bf16(af[mt], bf[nt], acc1[mt][nt], 0, 0, 0);
            if (st + 1 < S1) {
#pragma unroll
                for (int nt = 0; nt < NT1; ++nt) bf[nt] = bnx[nt];
            }
        }
    }
    __syncthreads();  // As dead; T1 overlay safe
    // epi1 -> T1 (LDS)
#pragma unroll
    for (int nt = 0; nt < NT1; ++nt) {
        int c = ch1 + nt * 16 + l15;
        float s, sh;
        epi_coeff(mode1, c, b1, g1, be1, mu1, var1, &s, &sh);
#pragma unroll
        for (int mt = 0; mt < 4; ++mt) {
            int rl = mt * 16 + quad * 4;
#pragma unroll
            for (int r = 0; r < 4; ++r) {
                float v = acc1[mt][nt][r] * s + sh;
                if (mode1 != 2) v = fmaxf(v, 0.f);
                T1[(rl + r) * LT1 + c] = f2bf(v);
            }
        }
    }
    __syncthreads();

    // ---- stage 2: A from T1 (LDS), B depth-1 pipelined, barrier-free loop ----
    f32x4 acc2[4][NT2] = {};
    bshort8 bnx2[NT2];
#pragma unroll
    for (int ks = 0; ks < S2; ++ks) {
        if (ks + 1 < S2) loadB2(ks + 1, bnx2);
        bshort8 af[4];
#pragma unroll
        for (int mt = 0; mt < 4; ++mt)
            af[mt] = *(const bshort8*)(&T1[(mt * 16 + l15) * LT1 + ks * 32 + quad * 8]);
#pragma unroll
        for (int nt = 0; nt < NT2; ++nt)
#pragma unroll
            for (int mt = 0; mt < 4; ++mt)
                acc2[mt][nt] = __builtin_amdgcn_mfma_f32_16x16x32_bf16(af[mt], bf2[nt], acc2[mt][nt], 0, 0, 0);
        if (ks + 1 < S2) {
#pragma unroll
            for (int nt = 0; nt < NT2; ++nt) bf2[nt] = bnx2[nt];
        }
    }
    __syncthreads();  // T1 dead; Ep overlay safe

    unsigned short* Ep = T1;
#pragma unroll
    for (int nt = 0; nt < NT2; ++nt) {
        int c = ch2 + nt * 16 + l15;
        float s, sh;
        epi_coeff(mode2, c, b2, g2, be2, mu2, var2, &s, &sh);
#pragma unroll
        for (int mt = 0; mt < 4; ++mt) {
            int rl = mt * 16 + quad * 4;
#pragma unroll
            for (int r = 0; r < 4; ++r) {
                float v = acc2[mt][nt][r] * s + sh;
                if (mode2 != 2) v = fmaxf(v, 0.f);
                Ep[(rl + r) * LDE + c] = f2bf(v);
            }
        }
    }
    __syncthreads();
    constexpr int CGR = DH2 / 8;
    constexpr int NU = BM * CGR / 256;
#pragma unroll
    for (int u = 0; u < NU; ++u) {
        int idx2 = tid + 256 * u;
        int r = idx2 / CGR, cg = (idx2 % CGR) * 8;
        int grow = row0 + r;
        if (grow < M)
            *(uint4*)(C + (size_t)grow * DH2 + cg) = *(const uint4*)(&Ep[r * LDE + cg]);
    }
}

// ---------------- launch ----------------

extern "C" void kernel_launch(void* const* d_in, const int* in_sizes, int n_in,
                              void* d_out, int out_size, void* d_ws, size_t ws_size,
                              hipStream_t stream) {
    const float* x = (const float*)d_in[0];
    const int* ei = (const int*)d_in[1];
    const int* src = ei;
    const int* dst = ei + N_EDGES;
    const float* w[4][2];
    const float* b[4][2];
    const float* bng[4];
    const float* bnb[4];
    const float* bnm[4];
    const float* bnv[4];
    int idx = 2;
    for (int i = 0; i < 4; ++i) {
        w[i][0] = (const float*)d_in[idx++];
        b[i][0] = (const float*)d_in[idx++];
        w[i][1] = (const float*)d_in[idx++];
        b[i][1] = (const float*)d_in[idx++];
        bng[i] = (const float*)d_in[idx++];
        bnb[i] = (const float*)d_in[idx++];
        bnm[i] = (const float*)d_in[idx++];
        bnv[i] = (const float*)d_in[idx++];
    }
    const float* wc = (const float*)d_in[idx++];
    const float* bc = (const float*)d_in[idx++];
    float* out = (float*)d_out;

    char* ws = (char*)d_ws;
    size_t off = 0;
    auto alloc = [&](size_t bytes) {
        char* p = ws + off;
        off = (off + bytes + 255) & ~(size_t)255;
        return p;
    };
    int* deg = (int*)alloc((size_t)N_NODES * 4);
    int* rowptr = (int*)alloc((size_t)(N_NODES + 1) * 4);
    int* cnt = (int*)alloc((size_t)K_BUCK * PART_B * 4);
    int* bsum2 = (int*)alloc((size_t)K_BUCK * 4);
    int* col = (int*)alloc((size_t)N_EDGES * 4);
    uint2* P = (uint2*)alloc((size_t)N_EDGES * 8);
    unsigned short* bufA = (unsigned short*)alloc((size_t)N_NODES * 256 * 2);
    unsigned short* bufB = (unsigned short*)alloc((size_t)N_NODES * 256 * 2);
    unsigned short* bufC = (unsigned short*)alloc((size_t)N_NODES * 256 * 2);
    const int dims_in[4] = {256, 128, 256, 128};
    const int dims_h[4] = {128, 256, 128, 64};
    unsigned short* wt[4][2];
    unsigned short* wp[4][2];
    for (int L = 0; L < 4; ++L) {
        wt[L][0] = (unsigned short*)alloc((size_t)dims_in[L] * dims_h[L] * 2);
        wt[L][1] = (unsigned short*)alloc((size_t)dims_h[L] * dims_h[L] * 2);
        wp[L][0] = (unsigned short*)alloc((size_t)dims_in[L] * dims_h[L] * 2);
        wp[L][1] = (unsigned short*)alloc((size_t)dims_h[L] * dims_h[L] * 2);
    }
    (void)ws_size;

    // weight conversions: row-major transposed (wt) + fragment-packed (wp)
    WT8 p;
    for (int L = 0; L < 4; ++L) {
        p.src[L * 2] = w[L][0];     p.dst[L * 2] = wt[L][0];
        p.K[L * 2] = dims_in[L];    p.N[L * 2] = dims_h[L];
        p.src[L * 2 + 1] = w[L][1]; p.dst[L * 2 + 1] = wt[L][1];
        p.K[L * 2 + 1] = dims_h[L]; p.N[L * 2 + 1] = dims_h[L];
    }
    wtconv_kernel<<<dim3(256, 8), 256, 0, stream>>>(p);
    WT8 q = p;
    for (int L = 0; L < 4; ++L) {
        q.dst[L * 2] = wp[L][0];
        q.dst[L * 2 + 1] = wp[L][1];
    }
    wpconv_kernel<<<dim3(256, 8), 256, 0, stream>>>(q);

    // ---- CSR build ----
    hipMemsetAsync(deg, 0, (size_t)N_NODES * 4, stream);
    bucket_count_kernel<<<PART_B, 256, 0, stream>>>(dst, deg, cnt);
    scan_reduce_kernel<<<K_BUCK, 256, 0, stream>>>(cnt, bsum2, K_BUCK * PART_B);
    scan_bsum_kernel<<<1, 256, 0, stream>>>(bsum2, K_BUCK);
    scan_apply_kernel<<<K_BUCK, 256, 0, stream>>>(cnt, bsum2, cnt, K_BUCK * PART_B);
    partition_kernel<<<PART_B, 256, 0, stream>>>(src, dst, cnt, P);
    fine_scatter_kernel<<<K_BUCK, 256, 0, stream>>>(P, cnt, deg, rowptr, col);

    const int gx = (N_NODES + 127) / 128;       // 391
    const int gxp = ((gx + 7) / 8) * 8;         // 392
    const int gx64 = (N_NODES + 63) / 64;       // 782
    const int M = N_NODES;

    // ---- L1: G1 (fp32 x, 256->128 raw), agg@128+bias+relu, G2 packed (128->128 BN) ----
    mfma_gemm2_kernel<8, true, false><<<gxp, 256, 0, stream>>>(
        x, wt[0][0], nullptr, bufA, M, 256, 128, 2, gx, 1,
        nullptr, nullptr, nullptr, nullptr, nullptr, nullptr, nullptr);
    aggregate_bf16_kernel<16, true><<<(N_NODES + 15) / 16, 256, 0, stream>>>(
        bufA, rowptr, col, b[0][0], bufB, N_NODES);
    packed_gemm_kernel<128, 128><<<gx64, 256, 0, stream>>>(
        bufB, wp[0][1], 1, b[0][1], bng[0], bnb[0], bnm[0], bnv[0], bufC, M);

    // ---- L2: agg@128, fused MLP (128->256 relu -> 256 BN+relu) ----
    aggregate_bf16_kernel<16, false><<<(N_NODES + 15) / 16, 256, 0, stream>>>(
        bufC, rowptr, col, nullptr, bufA, N_NODES);
    fused_mlp_kernel<128, 256, 256><<<gx64, 256, 0, stream>>>(
        bufA, wp[1][0], wp[1][1],
        0, b[1][0], nullptr, nullptr, nullptr, nullptr,
        1, b[1][1], bng[1], bnb[1], bnm[1], bnv[1],
        bufC, M);

    // ---- L3: G1 packed (256->128 raw), agg@128+bias+relu ----
    packed_gemm_kernel<256, 128><<<gx64, 256, 0, stream>>>(
        bufC, wp[2][0], 2, nullptr, nullptr, nullptr, nullptr, nullptr, bufA, M);
    aggregate_bf16_kernel<16, true><<<(N_NODES + 15) / 16, 256, 0, stream>>>(
        bufA, rowptr, col, b[2][0], bufB, N_NODES);

    // ---- fused: L3 G2 (128->128 BN+relu) -> L4 G1 (128->64 raw) ----
    fused_mlp_kernel<128, 128, 64><<<gx64, 256, 0, stream>>>(
        bufB, wp[2][1], wp[3][0],
        1, b[2][1], bng[2], bnb[2], bnm[2], bnv[2],
        2, nullptr, nullptr, nullptr, nullptr, nullptr,
        bufA, M);

    // ---- L4: agg@64+bias+relu, G2+classifier ----
    aggregate_bf16_kernel<8, true><<<(N_NODES + 31) / 32, 256, 0, stream>>>(
        bufA, rowptr, col, b[3][0], bufB, N_NODES);
    mfma_gemm2_kernel<4, false, true><<<gxp, 256, 0, stream>>>(
        bufB, wt[3][1], b[3][1], nullptr, M, 64, 64, 1, gx, 1,
        bng[3], bnb[3], bnm[3], bnv[3], wc, bc, out);
}